// Round 2
// baseline (323.611 us; speedup 1.0000x reference)
//
#include <hip/hip_runtime.h>
#include <math.h>

#define A_NUM 8732
#define O_NUM 32
#define NEGPOS 3
#define NTHR 1024
#define NWAVE (NTHR / 64)

// one block per (batch, frame); 1024 threads = 16 waves/CU
__global__ __launch_bounds__(NTHR, 4) void mfbl_frame_kernel(
    const float* __restrict__ loc_data,   // [BF, A, 4]
    const float* __restrict__ conf_data,  // [BF, A, 2]
    const float* __restrict__ anchors,    // [A, 4] center form
    const float* __restrict__ targets,    // [BF, O, 5]
    float* __restrict__ ws, int BF)       // ws[0..BF): loss_l, ws[BF..2BF): loss_c
{
    const int frame = blockIdx.x;
    const int tid = threadIdx.x;
    const int lane = tid & 63;
    const int wid  = tid >> 6;

    __shared__ float4 s_tc[O_NUM];                 // truth corners (x1,y1,x2,y2)
    __shared__ float  s_ta[O_NUM];                 // truth area
    __shared__ float  s_lab[O_NUM];                // truth label
    __shared__ unsigned int s_key[A_NUM];          // per-anchor packed best (iou_hi | 31-o)
    __shared__ int s_bp[O_NUM];                    // per-truth forced anchor index
    __shared__ unsigned int s_tred[O_NUM][NWAVE];
    __shared__ float s_rl[NWAVE], s_rc[NWAVE];
    __shared__ int   s_rnp[NWAVE], s_rm[NWAVE];

    // load truths for this frame
    if (tid < O_NUM) {
        const float* t = targets + ((size_t)frame * O_NUM + tid) * 5;
        float x1 = t[0], y1 = t[1], x2 = t[2], y2 = t[3];
        s_tc[tid] = make_float4(x1, y1, x2, y2);
        s_ta[tid] = (x2 - x1) * (y2 - y1);
        s_lab[tid] = t[4];
    }
    __syncthreads();

    // ---------- pass 1: IoU with packed-key argmax ----------
    // key layout: [31:14] = top 18 bits of float(iou) (iou >= 0 so uint order == float order)
    //             low bits = tie-break index (bigger key -> smaller index, matching jnp first-max)
    unsigned int tb[O_NUM];
#pragma unroll
    for (int o = 0; o < O_NUM; ++o) tb[o] = 0u;

    for (int a = tid; a < A_NUM; a += NTHR) {
        const float4 pr = *(const float4*)(anchors + (size_t)a * 4);
        float hw = pr.z * 0.5f, hh = pr.w * 0.5f;
        float px1 = pr.x - hw, py1 = pr.y - hh;
        float px2 = pr.x + hw, py2 = pr.y + hh;
        float area_p = (px2 - px1) * (py2 - py1);
        unsigned int bestA = 0u;
        const unsigned int aT = 16383u - (unsigned int)a;   // 14-bit anchor tie-break
#pragma unroll
        for (int o = 0; o < O_NUM; ++o) {
            float4 t = s_tc[o];
            float ltx = fmaxf(t.x, px1);
            float lty = fmaxf(t.y, py1);
            float rbx = fminf(t.z, px2);
            float rby = fminf(t.w, py2);
            float w = fmaxf(rbx - ltx, 0.0f);
            float h = fmaxf(rby - lty, 0.0f);
            float inter = w * h;
            float uni = s_ta[o] + area_p - inter;
            float iou = inter * __builtin_amdgcn_rcpf(uni);
            unsigned int hi = __float_as_uint(iou) & 0xFFFFC000u;
            bestA = max(bestA, hi | (unsigned int)(31 - o));  // 5-bit truth tie-break
            tb[o]  = max(tb[o],  hi | aT);
        }
        s_key[a] = bestA;
    }

    // per-truth best-anchor reduce across block
#pragma unroll
    for (int o = 0; o < O_NUM; ++o) {
        unsigned int k = tb[o];
        for (int s = 32; s > 0; s >>= 1) {
            unsigned int k2 = __shfl_down(k, s);
            k = max(k, k2);
        }
        if (lane == 0) s_tred[o][wid] = k;
    }
    __syncthreads();
    if (tid < O_NUM) {
        unsigned int k = s_tred[tid][0];
        for (int w = 1; w < NWAVE; ++w) k = max(k, s_tred[tid][w]);
        s_bp[tid] = 16383 - (int)(k & 16383u);
    }
    __syncthreads();

    // ---------- pass 2: conf_t, losses ----------
    const float LOGEPS = -27.631021115928547f;  // log(1e-12)
    float l_sum = 0.0f, cpos = 0.0f;
    int np_cnt = 0, m_cnt = 0;

    for (int a = tid; a < A_NUM; a += NTHR) {
        unsigned int k = s_key[a];
        int o = 31 - (int)(k & 31u);
        unsigned int hi = k & 0xFFFFC000u;
        int forced = -1;
#pragma unroll
        for (int t = 0; t < O_NUM; ++t)
            if (s_bp[t] == a) forced = t;   // last truth wins (scatter last-write)
        int conf;
        if (forced >= 0) { o = forced; conf = (int)s_lab[o] + 1; }
        else             { conf = (hi < 0x3F000000u) ? 0 : ((int)s_lab[o] + 1); }

        const float2 cd = *(const float2*)(conf_data + ((size_t)frame * A_NUM + a) * 2);
        int pred = (cd.y > cd.x) ? 1 : 0;   // argmax, first occurrence on ties

        if (conf > 0) {
            np_cnt++;
            const float4 pr = *(const float4*)(anchors + (size_t)a * 4);
            const float4 ld = *(const float4*)(loc_data + ((size_t)frame * A_NUM + a) * 4);
            float4 t = s_tc[o];
            float gx = ((t.x + t.z) * 0.5f - pr.x) / (0.1f * pr.z);
            float gy = ((t.y + t.w) * 0.5f - pr.y) / (0.1f * pr.w);
            float gw = logf((t.z - t.x) / pr.z) / 0.2f;
            float gh = logf((t.w - t.y) / pr.w) / 0.2f;
            float d0 = ld.x - gx, d1 = ld.y - gy, d2 = ld.z - gw, d3 = ld.w - gh;
            float a0 = fabsf(d0), a1 = fabsf(d1), a2 = fabsf(d2), a3 = fabsf(d3);
            float s0 = (a0 < 1.0f) ? 0.5f * d0 * d0 : a0 - 0.5f;
            float s1 = (a1 < 1.0f) ? 0.5f * d1 * d1 : a1 - 0.5f;
            float s2 = (a2 < 1.0f) ? 0.5f * d2 * d2 : a2 - 0.5f;
            float s3 = (a3 < 1.0f) ? 0.5f * d3 * d3 : a3 - 0.5f;
            l_sum += s0 + s1 + s2 + s3;
            float tgt = (float)conf;
            float logp   = (pred == 0) ? LOGEPS : 0.0f;
            float log1mp = (pred == 1) ? LOGEPS : 0.0f;
            cpos += -(tgt * logp + (1.0f - tgt) * log1mp);
        } else {
            m_cnt += pred;  // negative with lc > log2  <=>  pred==1
        }
    }

    // block reduce the four scalars
    for (int s = 32; s > 0; s >>= 1) {
        l_sum  += __shfl_down(l_sum, s);
        cpos   += __shfl_down(cpos, s);
        np_cnt += __shfl_down(np_cnt, s);
        m_cnt  += __shfl_down(m_cnt, s);
    }
    if (lane == 0) { s_rl[wid] = l_sum; s_rc[wid] = cpos; s_rnp[wid] = np_cnt; s_rm[wid] = m_cnt; }
    __syncthreads();
    if (tid == 0) {
        float L = 0.0f, C = 0.0f; int np = 0, m = 0;
        for (int w = 0; w < NWAVE; ++w) { L += s_rl[w]; C += s_rc[w]; np += s_rnp[w]; m += s_rm[w]; }
        int num_neg = min(NEGPOS * np, A_NUM - 1);
        int nsel = min(num_neg, m);   // selected negatives that are mispredicted
        ws[frame]      = L;
        ws[BF + frame] = C + 27.631021115928547f * (float)nsel;
    }
}

__global__ void mfbl_reduce_kernel(const float* __restrict__ ws, float* __restrict__ out, int n) {
    int tid = threadIdx.x;
    float a = (tid < n) ? ws[tid] : 0.0f;
    float b = (tid < n) ? ws[n + tid] : 0.0f;
    for (int s = 32; s > 0; s >>= 1) {
        a += __shfl_down(a, s);
        b += __shfl_down(b, s);
    }
    __shared__ float sa[4], sb[4];
    int lane = tid & 63, wid = tid >> 6;
    if (lane == 0) { sa[wid] = a; sb[wid] = b; }
    __syncthreads();
    if (tid == 0) {
        float A = 0.0f, B = 0.0f;
        for (int w = 0; w < 4; ++w) { A += sa[w]; B += sb[w]; }
        out[0] = A;
        out[1] = B;
    }
}

extern "C" void kernel_launch(void* const* d_in, const int* in_sizes, int n_in,
                              void* d_out, int out_size, void* d_ws, size_t ws_size,
                              hipStream_t stream) {
    const float* loc     = (const float*)d_in[0];
    const float* conf    = (const float*)d_in[1];
    const float* anchors = (const float*)d_in[2];
    const float* targets = (const float*)d_in[3];
    float* out = (float*)d_out;
    float* ws  = (float*)d_ws;

    const int BF = in_sizes[3] / (O_NUM * 5);   // 32*8 = 256 frames

    mfbl_frame_kernel<<<BF, NTHR, 0, stream>>>(loc, conf, anchors, targets, ws, BF);
    mfbl_reduce_kernel<<<1, 256, 0, stream>>>(ws, out, BF);
}

// Round 3
// 140.072 us; speedup vs baseline: 2.3103x; 2.3103x over previous
//
#include <hip/hip_runtime.h>
#include <math.h>

#define A_NUM 8732
#define O_NUM 32
#define NEGPOS 3
#define NTHR 512
#define NWAVE (NTHR / 64)
#define TILE 4
#define MAIN_END (NTHR * TILE * (A_NUM / (NTHR * TILE)))   // 8192

// one block per (batch, frame); 512 threads
__global__ __launch_bounds__(NTHR) void mfbl_frame_kernel(
    const float* __restrict__ loc_data,   // [BF, A, 4]
    const float* __restrict__ conf_data,  // [BF, A, 2]
    const float* __restrict__ anchors,    // [A, 4] center form
    const float* __restrict__ targets,    // [BF, O, 5]
    float* __restrict__ ws, int BF)       // ws[0..BF): loss_l, ws[BF..2BF): loss_c
{
    const int frame = blockIdx.x;
    const int tid = threadIdx.x;
    const int lane = tid & 63;
    const int wid  = tid >> 6;

    __shared__ float4 s_tc[O_NUM];                 // truth corners (x1,y1,x2,y2)
    __shared__ float  s_lab[O_NUM];                // truth label
    __shared__ unsigned int s_key[A_NUM];          // per-anchor packed best (iou_hi | 31-o)
    __shared__ unsigned char s_forced[A_NUM];      // per-anchor forced truth (255 = none)
    __shared__ int s_bp[O_NUM];                    // per-truth forced anchor index
    __shared__ unsigned int s_tred[O_NUM][NWAVE];
    __shared__ float s_rl[NWAVE], s_rc[NWAVE];
    __shared__ int   s_rnp[NWAVE], s_rm[NWAVE];

    // load truths for this frame
    if (tid < O_NUM) {
        const float* t = targets + ((size_t)frame * O_NUM + tid) * 5;
        s_tc[tid] = make_float4(t[0], t[1], t[2], t[3]);
        s_lab[tid] = t[4];
    }
    __syncthreads();

    // ---------- pass 1: IoU with packed-key argmax ----------
    // key layout: [31:14] = top 18 bits of float(iou); low bits = tie-break
    // (bigger key -> smaller index, matching jnp first-occurrence argmax)
    unsigned int tb[O_NUM];
#pragma unroll
    for (int o = 0; o < O_NUM; ++o) tb[o] = 0u;

    // main tiles: 4 anchors per thread held in registers, truths broadcast once per tile
    for (int base = 0; base < MAIN_END; base += NTHR * TILE) {
        float px1[TILE], py1[TILE], px2[TILE], py2[TILE], ap[TILE];
        unsigned int bestA[TILE], aT[TILE];
#pragma unroll
        for (int j = 0; j < TILE; ++j) {
            const int a = base + tid + j * NTHR;
            const float4 pr = *(const float4*)(anchors + (size_t)a * 4);
            float hw = pr.z * 0.5f, hh = pr.w * 0.5f;
            px1[j] = pr.x - hw; py1[j] = pr.y - hh;
            px2[j] = pr.x + hw; py2[j] = pr.y + hh;
            ap[j] = (px2[j] - px1[j]) * (py2[j] - py1[j]);
            bestA[j] = 0u;
            aT[j] = 16383u - (unsigned int)a;
        }
#pragma unroll
        for (int o = 0; o < O_NUM; ++o) {
            const float4 t = s_tc[o];
            const float ta = (t.z - t.x) * (t.w - t.y);
            const unsigned int oc = (unsigned int)(31 - o);
#pragma unroll
            for (int j = 0; j < TILE; ++j) {
                float w = __saturatef(fminf(t.z, px2[j]) - fmaxf(t.x, px1[j]));
                float h = __saturatef(fminf(t.w, py2[j]) - fmaxf(t.y, py1[j]));
                float inter = w * h;
                float uni = (ta + ap[j]) - inter;
                float iou = inter * __builtin_amdgcn_rcpf(uni);
                unsigned int hi = __float_as_uint(iou) & 0xFFFFC000u;
                bestA[j] = max(bestA[j], hi | oc);
                tb[o]    = max(tb[o],  hi | aT[j]);
            }
        }
#pragma unroll
        for (int j = 0; j < TILE; ++j) {
            const int a = base + tid + j * NTHR;
            s_key[a] = bestA[j];
            s_forced[a] = 255;
        }
    }
    // tail anchors (strided, guarded)
    for (int a = MAIN_END + tid; a < A_NUM; a += NTHR) {
        const float4 pr = *(const float4*)(anchors + (size_t)a * 4);
        float hw = pr.z * 0.5f, hh = pr.w * 0.5f;
        float px1 = pr.x - hw, py1 = pr.y - hh;
        float px2 = pr.x + hw, py2 = pr.y + hh;
        float area_p = (px2 - px1) * (py2 - py1);
        unsigned int bestA = 0u;
        const unsigned int aT = 16383u - (unsigned int)a;
#pragma unroll
        for (int o = 0; o < O_NUM; ++o) {
            const float4 t = s_tc[o];
            const float ta = (t.z - t.x) * (t.w - t.y);
            float w = __saturatef(fminf(t.z, px2) - fmaxf(t.x, px1));
            float h = __saturatef(fminf(t.w, py2) - fmaxf(t.y, py1));
            float inter = w * h;
            float uni = (ta + area_p) - inter;
            float iou = inter * __builtin_amdgcn_rcpf(uni);
            unsigned int hi = __float_as_uint(iou) & 0xFFFFC000u;
            bestA = max(bestA, hi | (unsigned int)(31 - o));
            tb[o] = max(tb[o], hi | aT);
        }
        s_key[a] = bestA;
        s_forced[a] = 255;
    }

    // per-truth best-anchor reduce across block
#pragma unroll
    for (int o = 0; o < O_NUM; ++o) {
        unsigned int k = tb[o];
        for (int s = 32; s > 0; s >>= 1)
            k = max(k, (unsigned int)__shfl_down(k, s));
        if (lane == 0) s_tred[o][wid] = k;
    }
    __syncthreads();
    if (tid < O_NUM) {
        unsigned int k = s_tred[tid][0];
        for (int w = 1; w < NWAVE; ++w) k = max(k, s_tred[tid][w]);
        s_bp[tid] = 16383 - (int)(k & 16383u);
    }
    __syncthreads();
    if (tid == 0) {
        // sequential so later truths overwrite earlier (scatter last-write semantics)
        for (int o = 0; o < O_NUM; ++o) s_forced[s_bp[o]] = (unsigned char)o;
    }
    __syncthreads();

    // ---------- pass 2: conf_t, losses ----------
    const float LOGEPS = -27.631021115928547f;  // log(1e-12)
    float l_sum = 0.0f, cpos = 0.0f;
    int np_cnt = 0, m_cnt = 0;

    for (int a = tid; a < A_NUM; a += NTHR) {
        unsigned int k = s_key[a];
        int o = 31 - (int)(k & 31u);
        unsigned int hi = k & 0xFFFFC000u;
        int f = (int)s_forced[a];
        int conf;
        if (f != 255) { o = f; conf = (int)s_lab[o] + 1; }
        else          { conf = (hi < 0x3F000000u) ? 0 : ((int)s_lab[o] + 1); }

        const float2 cd = *(const float2*)(conf_data + ((size_t)frame * A_NUM + a) * 2);
        int pred = (cd.y > cd.x) ? 1 : 0;   // argmax, first occurrence on ties

        if (conf > 0) {
            np_cnt++;
            const float4 pr = *(const float4*)(anchors + (size_t)a * 4);
            const float4 ld = *(const float4*)(loc_data + ((size_t)frame * A_NUM + a) * 4);
            float4 t = s_tc[o];
            float gx = ((t.x + t.z) * 0.5f - pr.x) / (0.1f * pr.z);
            float gy = ((t.y + t.w) * 0.5f - pr.y) / (0.1f * pr.w);
            float gw = logf((t.z - t.x) / pr.z) / 0.2f;
            float gh = logf((t.w - t.y) / pr.w) / 0.2f;
            float d0 = ld.x - gx, d1 = ld.y - gy, d2 = ld.z - gw, d3 = ld.w - gh;
            float a0 = fabsf(d0), a1 = fabsf(d1), a2 = fabsf(d2), a3 = fabsf(d3);
            float s0 = (a0 < 1.0f) ? 0.5f * d0 * d0 : a0 - 0.5f;
            float s1 = (a1 < 1.0f) ? 0.5f * d1 * d1 : a1 - 0.5f;
            float s2 = (a2 < 1.0f) ? 0.5f * d2 * d2 : a2 - 0.5f;
            float s3 = (a3 < 1.0f) ? 0.5f * d3 * d3 : a3 - 0.5f;
            l_sum += s0 + s1 + s2 + s3;
            float tgt = (float)conf;
            float logp   = (pred == 0) ? LOGEPS : 0.0f;
            float log1mp = (pred == 1) ? LOGEPS : 0.0f;
            cpos += -(tgt * logp + (1.0f - tgt) * log1mp);
        } else {
            m_cnt += pred;  // negative with lc > log2  <=>  pred==1
        }
    }

    // block reduce the four scalars
    for (int s = 32; s > 0; s >>= 1) {
        l_sum  += __shfl_down(l_sum, s);
        cpos   += __shfl_down(cpos, s);
        np_cnt += __shfl_down(np_cnt, s);
        m_cnt  += __shfl_down(m_cnt, s);
    }
    if (lane == 0) { s_rl[wid] = l_sum; s_rc[wid] = cpos; s_rnp[wid] = np_cnt; s_rm[wid] = m_cnt; }
    __syncthreads();
    if (tid == 0) {
        float L = 0.0f, C = 0.0f; int np = 0, m = 0;
        for (int w = 0; w < NWAVE; ++w) { L += s_rl[w]; C += s_rc[w]; np += s_rnp[w]; m += s_rm[w]; }
        int num_neg = min(NEGPOS * np, A_NUM - 1);
        int nsel = min(num_neg, m);   // selected negatives that are mispredicted
        ws[frame]      = L;
        ws[BF + frame] = C + 27.631021115928547f * (float)nsel;
    }
}

__global__ void mfbl_reduce_kernel(const float* __restrict__ ws, float* __restrict__ out, int n) {
    int tid = threadIdx.x;
    float a = (tid < n) ? ws[tid] : 0.0f;
    float b = (tid < n) ? ws[n + tid] : 0.0f;
    for (int s = 32; s > 0; s >>= 1) {
        a += __shfl_down(a, s);
        b += __shfl_down(b, s);
    }
    __shared__ float sa[4], sb[4];
    int lane = tid & 63, wid = tid >> 6;
    if (lane == 0) { sa[wid] = a; sb[wid] = b; }
    __syncthreads();
    if (tid == 0) {
        float A = 0.0f, B = 0.0f;
        for (int w = 0; w < 4; ++w) { A += sa[w]; B += sb[w]; }
        out[0] = A;
        out[1] = B;
    }
}

extern "C" void kernel_launch(void* const* d_in, const int* in_sizes, int n_in,
                              void* d_out, int out_size, void* d_ws, size_t ws_size,
                              hipStream_t stream) {
    const float* loc     = (const float*)d_in[0];
    const float* conf    = (const float*)d_in[1];
    const float* anchors = (const float*)d_in[2];
    const float* targets = (const float*)d_in[3];
    float* out = (float*)d_out;
    float* ws  = (float*)d_ws;

    const int BF = in_sizes[3] / (O_NUM * 5);   // 32*8 = 256 frames

    mfbl_frame_kernel<<<BF, NTHR, 0, stream>>>(loc, conf, anchors, targets, ws, BF);
    mfbl_reduce_kernel<<<1, 256, 0, stream>>>(ws, out, BF);
}

// Round 4
// 112.827 us; speedup vs baseline: 2.8682x; 1.2415x over previous
//
#include <hip/hip_runtime.h>
#include <math.h>

#define A_NUM 8732
#define O_NUM 32
#define NEGPOS 3
#define NTHR 512
#define NWAVE (NTHR / 64)

// one block per (batch, frame); 512 threads
__global__ __launch_bounds__(NTHR) void mfbl_frame_kernel(
    const float* __restrict__ loc_data,   // [BF, A, 4]
    const float* __restrict__ conf_data,  // [BF, A, 2]
    const float* __restrict__ anchors,    // [A, 4] center form
    const float* __restrict__ targets,    // [BF, O, 5]
    float* __restrict__ ws, int BF)       // ws[0..BF): loss_l, ws[BF..2BF): loss_c
{
    const int frame = blockIdx.x;
    const int tid = threadIdx.x;
    const int lane = tid & 63;
    const int wid  = tid >> 6;

    __shared__ float4 s_tc[O_NUM];                 // truth corners (x1,y1,x2,y2)
    __shared__ float  s_ta[O_NUM];                 // truth area
    __shared__ float  s_lab[O_NUM];                // truth label
    __shared__ unsigned int s_key[A_NUM];          // per-anchor packed best (iou_hi | 31-o)
    __shared__ unsigned char s_forced[A_NUM];      // per-anchor forced truth (255 = none)
    __shared__ int s_bp[O_NUM];                    // per-truth forced anchor index
    __shared__ unsigned int s_tred[O_NUM][NWAVE];
    __shared__ float s_rl[NWAVE], s_rc[NWAVE];
    __shared__ int   s_rnp[NWAVE], s_rm[NWAVE];

    // load truths for this frame
    if (tid < O_NUM) {
        const float* t = targets + ((size_t)frame * O_NUM + tid) * 5;
        float x1 = t[0], y1 = t[1], x2 = t[2], y2 = t[3];
        s_tc[tid] = make_float4(x1, y1, x2, y2);
        s_ta[tid] = (x2 - x1) * (y2 - y1);
        s_lab[tid] = t[4];
    }
    __syncthreads();

    // ---------- pass 1: IoU with packed-key argmax ----------
    // key layout: [31:14] = top 18 bits of float(iou); low bits = tie-break
    // (bigger key -> smaller index, matching jnp first-occurrence argmax)
    unsigned int tb[O_NUM];
#pragma unroll
    for (int o = 0; o < O_NUM; ++o) tb[o] = 0u;

    for (int a = tid; a < A_NUM; a += NTHR) {
        const float4 pr = *(const float4*)(anchors + (size_t)a * 4);
        const float hw = pr.z * 0.5f, hh = pr.w * 0.5f;
        const float px1 = pr.x - hw, py1 = pr.y - hh;
        const float px2 = pr.x + hw, py2 = pr.y + hh;
        const float ap = (px2 - px1) * (py2 - py1);
        unsigned int bestA = 0u;
        const unsigned int aT = 16383u - (unsigned int)a;   // 14-bit anchor tie-break
#pragma unroll
        for (int o = 0; o < O_NUM; ++o) {
            const float4 t = s_tc[o];
            float w = __saturatef(fminf(t.z, px2) - fmaxf(t.x, px1));
            float h = __saturatef(fminf(t.w, py2) - fmaxf(t.y, py1));
            float inter = w * h;
            float uni = (s_ta[o] + ap) - inter;
            float iou = inter * __builtin_amdgcn_rcpf(uni);
            unsigned int hi = __float_as_uint(iou) & 0xFFFFC000u;
            bestA = max(bestA, hi | (unsigned int)(31 - o));  // 5-bit truth tie-break
            tb[o]  = max(tb[o],  hi | aT);
        }
        s_key[a] = bestA;
        s_forced[a] = 255;
    }

    // per-truth best-anchor reduce across block
#pragma unroll
    for (int o = 0; o < O_NUM; ++o) {
        unsigned int k = tb[o];
        for (int s = 32; s > 0; s >>= 1)
            k = max(k, (unsigned int)__shfl_down(k, s));
        if (lane == 0) s_tred[o][wid] = k;
    }
    __syncthreads();
    if (tid < O_NUM) {
        unsigned int k = s_tred[tid][0];
        for (int w = 1; w < NWAVE; ++w) k = max(k, s_tred[tid][w]);
        s_bp[tid] = 16383 - (int)(k & 16383u);
    }
    __syncthreads();
    if (tid == 0) {
        // sequential so later truths overwrite earlier (scatter last-write semantics)
        for (int o = 0; o < O_NUM; ++o) s_forced[s_bp[o]] = (unsigned char)o;
    }
    __syncthreads();

    // ---------- pass 2: conf_t, losses ----------
    const float LOGEPS = -27.631021115928547f;  // log(1e-12)
    float l_sum = 0.0f, cpos = 0.0f;
    int np_cnt = 0, m_cnt = 0;

    for (int a = tid; a < A_NUM; a += NTHR) {
        unsigned int k = s_key[a];
        int o = 31 - (int)(k & 31u);
        unsigned int hi = k & 0xFFFFC000u;
        int f = (int)s_forced[a];
        int conf;
        if (f != 255) { o = f; conf = (int)s_lab[o] + 1; }
        else          { conf = (hi < 0x3F000000u) ? 0 : ((int)s_lab[o] + 1); }

        const float2 cd = *(const float2*)(conf_data + ((size_t)frame * A_NUM + a) * 2);
        int pred = (cd.y > cd.x) ? 1 : 0;   // argmax, first occurrence on ties

        if (conf > 0) {
            np_cnt++;
            const float4 pr = *(const float4*)(anchors + (size_t)a * 4);
            const float4 ld = *(const float4*)(loc_data + ((size_t)frame * A_NUM + a) * 4);
            float4 t = s_tc[o];
            float gx = ((t.x + t.z) * 0.5f - pr.x) / (0.1f * pr.z);
            float gy = ((t.y + t.w) * 0.5f - pr.y) / (0.1f * pr.w);
            float gw = logf((t.z - t.x) / pr.z) / 0.2f;
            float gh = logf((t.w - t.y) / pr.w) / 0.2f;
            float d0 = ld.x - gx, d1 = ld.y - gy, d2 = ld.z - gw, d3 = ld.w - gh;
            float a0 = fabsf(d0), a1 = fabsf(d1), a2 = fabsf(d2), a3 = fabsf(d3);
            float s0 = (a0 < 1.0f) ? 0.5f * d0 * d0 : a0 - 0.5f;
            float s1 = (a1 < 1.0f) ? 0.5f * d1 * d1 : a1 - 0.5f;
            float s2 = (a2 < 1.0f) ? 0.5f * d2 * d2 : a2 - 0.5f;
            float s3 = (a3 < 1.0f) ? 0.5f * d3 * d3 : a3 - 0.5f;
            l_sum += s0 + s1 + s2 + s3;
            float tgt = (float)conf;
            float logp   = (pred == 0) ? LOGEPS : 0.0f;
            float log1mp = (pred == 1) ? LOGEPS : 0.0f;
            cpos += -(tgt * logp + (1.0f - tgt) * log1mp);
        } else {
            m_cnt += pred;  // negative with lc > log2  <=>  pred==1
        }
    }

    // block reduce the four scalars
    for (int s = 32; s > 0; s >>= 1) {
        l_sum  += __shfl_down(l_sum, s);
        cpos   += __shfl_down(cpos, s);
        np_cnt += __shfl_down(np_cnt, s);
        m_cnt  += __shfl_down(m_cnt, s);
    }
    if (lane == 0) { s_rl[wid] = l_sum; s_rc[wid] = cpos; s_rnp[wid] = np_cnt; s_rm[wid] = m_cnt; }
    __syncthreads();
    if (tid == 0) {
        float L = 0.0f, C = 0.0f; int np = 0, m = 0;
        for (int w = 0; w < NWAVE; ++w) { L += s_rl[w]; C += s_rc[w]; np += s_rnp[w]; m += s_rm[w]; }
        int num_neg = min(NEGPOS * np, A_NUM - 1);
        int nsel = min(num_neg, m);   // selected negatives that are mispredicted
        ws[frame]      = L;
        ws[BF + frame] = C + 27.631021115928547f * (float)nsel;
    }
}

__global__ void mfbl_reduce_kernel(const float* __restrict__ ws, float* __restrict__ out, int n) {
    int tid = threadIdx.x;
    float a = (tid < n) ? ws[tid] : 0.0f;
    float b = (tid < n) ? ws[n + tid] : 0.0f;
    for (int s = 32; s > 0; s >>= 1) {
        a += __shfl_down(a, s);
        b += __shfl_down(b, s);
    }
    __shared__ float sa[4], sb[4];
    int lane = tid & 63, wid = tid >> 6;
    if (lane == 0) { sa[wid] = a; sb[wid] = b; }
    __syncthreads();
    if (tid == 0) {
        float A = 0.0f, B = 0.0f;
        for (int w = 0; w < 4; ++w) { A += sa[w]; B += sb[w]; }
        out[0] = A;
        out[1] = B;
    }
}

extern "C" void kernel_launch(void* const* d_in, const int* in_sizes, int n_in,
                              void* d_out, int out_size, void* d_ws, size_t ws_size,
                              hipStream_t stream) {
    const float* loc     = (const float*)d_in[0];
    const float* conf    = (const float*)d_in[1];
    const float* anchors = (const float*)d_in[2];
    const float* targets = (const float*)d_in[3];
    float* out = (float*)d_out;
    float* ws  = (float*)d_ws;

    const int BF = in_sizes[3] / (O_NUM * 5);   // 32*8 = 256 frames

    mfbl_frame_kernel<<<BF, NTHR, 0, stream>>>(loc, conf, anchors, targets, ws, BF);
    mfbl_reduce_kernel<<<1, 256, 0, stream>>>(ws, out, BF);
}

// Round 5
// 104.697 us; speedup vs baseline: 3.0909x; 1.0777x over previous
//
#include <hip/hip_runtime.h>
#include <math.h>

#define A_NUM 8732
#define O_NUM 32
#define NEGPOS 3
#define NTHR 512
#define NWAVE (NTHR / 64)
#define ASPLIT 4
#define APB ((A_NUM + ASPLIT - 1) / ASPLIT)   // 2183
#define JMAX ((APB + NTHR - 1) / NTHR)        // 5
#define LOGEPS_F (-27.631021115928547f)       // log(1e-12)

__device__ __forceinline__ float rfl(float x) {
    return __int_as_float(__builtin_amdgcn_readfirstlane(__float_as_int(x)));
}

// top-18 bits of IoU as a uint (IoU >= 0 so uint order == float order)
__device__ __forceinline__ unsigned int iou_hi(float tx1, float ty1, float tx2, float ty2, float ta,
                                               float px1, float py1, float px2, float py2, float ap) {
    float w = __saturatef(fminf(tx2, px2) - fmaxf(tx1, px1));
    float h = __saturatef(fminf(ty2, py2) - fmaxf(ty1, py1));
    float inter = w * h;
    float uni = (ta + ap) - inter;
    float iou = inter * __builtin_amdgcn_rcpf(uni);
    return __float_as_uint(iou) & 0xFFFFC000u;
}

__device__ __forceinline__ float sl1_sum(float4 t, float4 pr, float4 ld) {
    float gx = ((t.x + t.z) * 0.5f - pr.x) / (0.1f * pr.z);
    float gy = ((t.y + t.w) * 0.5f - pr.y) / (0.1f * pr.w);
    float gw = logf((t.z - t.x) / pr.z) / 0.2f;
    float gh = logf((t.w - t.y) / pr.w) / 0.2f;
    float d0 = ld.x - gx, d1 = ld.y - gy, d2 = ld.z - gw, d3 = ld.w - gh;
    float a0 = fabsf(d0), a1 = fabsf(d1), a2 = fabsf(d2), a3 = fabsf(d3);
    float s0 = (a0 < 1.0f) ? 0.5f * d0 * d0 : a0 - 0.5f;
    float s1 = (a1 < 1.0f) ? 0.5f * d1 * d1 : a1 - 0.5f;
    float s2 = (a2 < 1.0f) ? 0.5f * d2 * d2 : a2 - 0.5f;
    float s3 = (a3 < 1.0f) ? 0.5f * d3 * d3 : a3 - 0.5f;
    return s0 + s1 + s2 + s3;
}

__device__ __forceinline__ float bce_pos(int pred, float tgt) {
    float logp   = (pred == 0) ? LOGEPS_F : 0.0f;
    float log1mp = (pred == 1) ? LOGEPS_F : 0.0f;
    return -(tgt * logp + (1.0f - tgt) * log1mp);
}

// K1: grid = BF*ASPLIT blocks; block handles APB anchors of one frame.
// Computes per-truth partial best-anchor keys and UNFORCED partial losses.
__global__ __launch_bounds__(NTHR) void mfbl_k1(
    const float* __restrict__ loc_data, const float* __restrict__ conf_data,
    const float* __restrict__ anchors, const float* __restrict__ targets,
    unsigned int* __restrict__ g_tred, float4* __restrict__ g_part)
{
    const int bid = blockIdx.x;
    const int frame = bid >> 2;
    const int split = bid & 3;
    const int a_lo = split * APB;
    const int a_hi = min(a_lo + APB, A_NUM);
    const int tid = threadIdx.x;
    const int lane = tid & 63, wid = tid >> 6;

    __shared__ float4 s_tc[O_NUM];
    __shared__ float s_ta[O_NUM], s_lab[O_NUM];
    __shared__ unsigned int s_tred[O_NUM][NWAVE];
    __shared__ float s_r[4][NWAVE];

    if (tid < O_NUM) {
        const float* t = targets + ((size_t)frame * O_NUM + tid) * 5;
        float x1 = t[0], y1 = t[1], x2 = t[2], y2 = t[3];
        s_tc[tid] = make_float4(x1, y1, x2, y2);
        s_ta[tid] = (x2 - x1) * (y2 - y1);
        s_lab[tid] = t[4];
    }
    __syncthreads();

    // anchors in registers (clamped duplicates for tail lanes; their per-truth
    // keys can never win because aT is strictly smaller than the real copy's)
    float px1[JMAX], py1[JMAX], px2[JMAX], py2[JMAX], ap[JMAX];
    unsigned int bestA[JMAX], aT[JMAX];
#pragma unroll
    for (int j = 0; j < JMAX; ++j) {
        int a = a_lo + tid + j * NTHR;
        int ac = min(a, a_hi - 1);
        float4 pr = *(const float4*)(anchors + (size_t)ac * 4);
        float hw = pr.z * 0.5f, hh = pr.w * 0.5f;
        px1[j] = pr.x - hw; py1[j] = pr.y - hh;
        px2[j] = pr.x + hw; py2[j] = pr.y + hh;
        ap[j] = (px2[j] - px1[j]) * (py2[j] - py1[j]);
        bestA[j] = 0u;
        aT[j] = 16383u - (unsigned int)a;
    }

    // 4 chunks of 8 truths, truths hoisted to SGPRs -> zero LDS in hot loop
#pragma unroll
    for (int c = 0; c < 4; ++c) {
        float tx1[8], ty1[8], tx2[8], ty2[8], tta[8];
        unsigned int tb8[8];
#pragma unroll
        for (int o8 = 0; o8 < 8; ++o8) {
            float4 t = s_tc[c * 8 + o8];
            tx1[o8] = rfl(t.x); ty1[o8] = rfl(t.y);
            tx2[o8] = rfl(t.z); ty2[o8] = rfl(t.w);
            tta[o8] = rfl(s_ta[c * 8 + o8]);
            tb8[o8] = 0u;
        }
#pragma unroll
        for (int o8 = 0; o8 < 8; ++o8) {
            const unsigned int oc = (unsigned int)(31 - (c * 8 + o8));
#pragma unroll
            for (int j = 0; j < JMAX; ++j) {
                unsigned int hi = iou_hi(tx1[o8], ty1[o8], tx2[o8], ty2[o8], tta[o8],
                                         px1[j], py1[j], px2[j], py2[j], ap[j]);
                bestA[j] = max(bestA[j], hi | oc);
                tb8[o8]  = max(tb8[o8], hi | aT[j]);
            }
        }
#pragma unroll
        for (int o8 = 0; o8 < 8; ++o8) {
            unsigned int k = tb8[o8];
            for (int s = 32; s > 0; s >>= 1)
                k = max(k, (unsigned int)__shfl_down((int)k, s));
            if (lane == 0) s_tred[c * 8 + o8][wid] = k;
        }
    }
    __syncthreads();
    if (tid < O_NUM) {
        unsigned int k = s_tred[tid][0];
        for (int w = 1; w < NWAVE; ++w) k = max(k, s_tred[tid][w]);
        g_tred[(size_t)bid * O_NUM + tid] = k;
    }

    // fused pass 2: unforced contributions
    float l_sum = 0.0f, cpos = 0.0f, np_cnt = 0.0f, m_cnt = 0.0f;
#pragma unroll
    for (int j = 0; j < JMAX; ++j) {
        int a = a_lo + tid + j * NTHR;
        if (a < a_hi) {
            unsigned int k = bestA[j];
            int o = 31 - (int)(k & 31u);
            unsigned int hi = k & 0xFFFFC000u;
            const float2 cd = *(const float2*)(conf_data + ((size_t)frame * A_NUM + a) * 2);
            int pred = (cd.y > cd.x) ? 1 : 0;
            int cv = (hi >= 0x3F000000u) ? (int)s_lab[o] + 1 : 0;
            if (cv > 0) {
                np_cnt += 1.0f;
                float4 pr = *(const float4*)(anchors + (size_t)a * 4);
                float4 ld = *(const float4*)(loc_data + ((size_t)frame * A_NUM + a) * 4);
                l_sum += sl1_sum(s_tc[o], pr, ld);
                cpos += bce_pos(pred, (float)cv);
            } else {
                m_cnt += (float)pred;   // negative with lc > log2 <=> pred==1
            }
        }
    }
    for (int s = 32; s > 0; s >>= 1) {
        l_sum  += __shfl_down(l_sum, s);
        cpos   += __shfl_down(cpos, s);
        np_cnt += __shfl_down(np_cnt, s);
        m_cnt  += __shfl_down(m_cnt, s);
    }
    if (lane == 0) { s_r[0][wid] = l_sum; s_r[1][wid] = cpos; s_r[2][wid] = np_cnt; s_r[3][wid] = m_cnt; }
    __syncthreads();
    if (tid == 0) {
        float L = 0, C = 0, NP = 0, M = 0;
        for (int w = 0; w < NWAVE; ++w) { L += s_r[0][w]; C += s_r[1][w]; NP += s_r[2][w]; M += s_r[3][w]; }
        g_part[bid] = make_float4(L, C, NP, M);
    }
}

// K2: grid = BF blocks x 64 threads. Reduce per-truth keys, apply forced-match
// corrections (<=32 anchors/frame), finalize per-frame losses.
__global__ __launch_bounds__(64) void mfbl_k2(
    const float* __restrict__ loc_data, const float* __restrict__ conf_data,
    const float* __restrict__ anchors, const float* __restrict__ targets,
    const unsigned int* __restrict__ g_tred, const float4* __restrict__ g_part,
    float* __restrict__ ws_l, float* __restrict__ ws_c)
{
    const int frame = blockIdx.x;
    const int tid = threadIdx.x;

    __shared__ float4 s_tc[O_NUM];
    __shared__ float s_ta[O_NUM], s_lab[O_NUM];
    __shared__ int s_bp[O_NUM];

    if (tid < O_NUM) {
        const float* t = targets + ((size_t)frame * O_NUM + tid) * 5;
        float x1 = t[0], y1 = t[1], x2 = t[2], y2 = t[3];
        s_tc[tid] = make_float4(x1, y1, x2, y2);
        s_ta[tid] = (x2 - x1) * (y2 - y1);
        s_lab[tid] = t[4];
        unsigned int k = 0u;
        for (int s = 0; s < ASPLIT; ++s)
            k = max(k, g_tred[((size_t)frame * ASPLIT + s) * O_NUM + tid]);
        s_bp[tid] = 16383 - (int)(k & 16383u);
    }
    __syncthreads();

    float dL = 0.0f, dC = 0.0f, dNP = 0.0f, dM = 0.0f;
    if (tid < O_NUM) {
        int a = s_bp[tid];
        bool owner = true;                       // last truth writing this anchor wins
        for (int o2 = tid + 1; o2 < O_NUM; ++o2)
            if (s_bp[o2] == a) owner = false;
        if (owner) {
            float4 pr = *(const float4*)(anchors + (size_t)a * 4);
            float hw = pr.z * 0.5f, hh = pr.w * 0.5f;
            float px1 = pr.x - hw, py1 = pr.y - hh;
            float px2 = pr.x + hw, py2 = pr.y + hh;
            float apn = (px2 - px1) * (py2 - py1);
            unsigned int bk = 0u;                // recompute unforced best truth
            for (int o2 = 0; o2 < O_NUM; ++o2) {
                float4 t = s_tc[o2];
                unsigned int hi = iou_hi(t.x, t.y, t.z, t.w, s_ta[o2], px1, py1, px2, py2, apn);
                bk = max(bk, hi | (unsigned int)(31 - o2));
            }
            int old_o = 31 - (int)(bk & 31u);
            unsigned int old_hi = bk & 0xFFFFC000u;
            int old_cv = (old_hi >= 0x3F000000u) ? (int)s_lab[old_o] + 1 : 0;
            const float2 cd = *(const float2*)(conf_data + ((size_t)frame * A_NUM + a) * 2);
            int pred = (cd.y > cd.x) ? 1 : 0;
            float4 ld = *(const float4*)(loc_data + ((size_t)frame * A_NUM + a) * 4);
            int new_cv = (int)s_lab[tid] + 1;
            dL = sl1_sum(s_tc[tid], pr, ld);
            dC = bce_pos(pred, (float)new_cv);
            dNP = 1.0f;
            if (old_cv > 0) {
                dL -= sl1_sum(s_tc[old_o], pr, ld);
                dC -= bce_pos(pred, (float)old_cv);
                dNP -= 1.0f;
            } else {
                dM -= (float)pred;
            }
        }
    }
    for (int s = 32; s > 0; s >>= 1) {
        dL += __shfl_down(dL, s);
        dC += __shfl_down(dC, s);
        dNP += __shfl_down(dNP, s);
        dM += __shfl_down(dM, s);
    }
    if (tid == 0) {
        float L = 0, C = 0, NP = 0, M = 0;
        for (int s = 0; s < ASPLIT; ++s) {
            float4 p = g_part[frame * ASPLIT + s];
            L += p.x; C += p.y; NP += p.z; M += p.w;
        }
        L += dL; C += dC; NP += dNP; M += dM;
        int np = (int)NP, m = (int)M;
        int num_neg = min(NEGPOS * np, A_NUM - 1);
        int nsel = min(num_neg, m);
        ws_l[frame] = L;
        ws_c[frame] = C + 27.631021115928547f * (float)nsel;
    }
}

__global__ void mfbl_k3(const float* __restrict__ ws_l, const float* __restrict__ ws_c,
                        float* __restrict__ out, int n) {
    int tid = threadIdx.x;
    float a = (tid < n) ? ws_l[tid] : 0.0f;
    float b = (tid < n) ? ws_c[tid] : 0.0f;
    for (int s = 32; s > 0; s >>= 1) {
        a += __shfl_down(a, s);
        b += __shfl_down(b, s);
    }
    __shared__ float sa[4], sb[4];
    int lane = tid & 63, wid = tid >> 6;
    if (lane == 0) { sa[wid] = a; sb[wid] = b; }
    __syncthreads();
    if (tid == 0) {
        float A = 0.0f, B = 0.0f;
        for (int w = 0; w < 4; ++w) { A += sa[w]; B += sb[w]; }
        out[0] = A;
        out[1] = B;
    }
}

extern "C" void kernel_launch(void* const* d_in, const int* in_sizes, int n_in,
                              void* d_out, int out_size, void* d_ws, size_t ws_size,
                              hipStream_t stream) {
    const float* loc     = (const float*)d_in[0];
    const float* conf    = (const float*)d_in[1];
    const float* anchors = (const float*)d_in[2];
    const float* targets = (const float*)d_in[3];
    float* out = (float*)d_out;
    (void)ws_size;

    const int BF = in_sizes[3] / (O_NUM * 5);   // 256 frames
    const int NBLK = BF * ASPLIT;

    unsigned int* g_tred = (unsigned int*)d_ws;                                   // NBLK*32 u32
    float4* g_part = (float4*)((char*)d_ws + (size_t)NBLK * O_NUM * 4);           // NBLK float4
    float* ws_l = (float*)((char*)d_ws + (size_t)NBLK * O_NUM * 4 + (size_t)NBLK * 16);
    float* ws_c = ws_l + BF;

    mfbl_k1<<<NBLK, NTHR, 0, stream>>>(loc, conf, anchors, targets, g_tred, g_part);
    mfbl_k2<<<BF, 64, 0, stream>>>(loc, conf, anchors, targets, g_tred, g_part, ws_l, ws_c);
    mfbl_k3<<<1, 256, 0, stream>>>(ws_l, ws_c, out, BF);
}